// Round 1
// baseline (717.144 us; speedup 1.0000x reference)
//
#include <hip/hip_runtime.h>

#define NN   50000        // nodes
#define EN   500000       // edges
#define DN   128          // node feature dim == edge feature dim
#define DIN  384          // 2*DN + DE
#define HID  64
#define NTILES 31250      // EN / 16 (exact)

typedef __attribute__((ext_vector_type(8))) short bf16x8;
typedef __attribute__((ext_vector_type(4))) float f32x4;

__device__ __forceinline__ short f2bf(float f) {
    union { float f; unsigned u; } v; v.f = f;
    return (short)((v.u + 0x7FFFu + ((v.u >> 16) & 1u)) >> 16);  // RNE
}

// W1 [384,64] f32 -> W1T [64][384] bf16 ; W2 [64,128] f32 -> W2T [128][64] bf16
__global__ void prep_weights(const float* __restrict__ W1, const float* __restrict__ W2,
                             short* __restrict__ W1T, short* __restrict__ W2T) {
    int i = blockIdx.x * 256 + threadIdx.x;
    if (i < DIN * HID) {
        int k = i / HID, n = i % HID;
        W1T[n * DIN + k] = f2bf(W1[i]);
    }
    if (i < HID * DN) {
        int k = i / DN, d = i % DN;
        W2T[d * HID + k] = f2bf(W2[i]);
    }
}

// x [NN,128] f32 -> xb [NN,128] bf16 (halves gather bytes, removes inner-loop converts)
__global__ void prep_x(const float* __restrict__ x, short* __restrict__ xb) {
    int i = blockIdx.x * 256 + threadIdx.x;   // one thread per 8 elements
    if (i >= NN * DN / 8) return;
    const float* p = x + (size_t)i * 8;
    f32x4 v0 = *(const f32x4*)p;
    f32x4 v1 = *(const f32x4*)(p + 4);
    bf16x8 o;
    o[0] = f2bf(v0[0]); o[1] = f2bf(v0[1]); o[2] = f2bf(v0[2]); o[3] = f2bf(v0[3]);
    o[4] = f2bf(v1[0]); o[5] = f2bf(v1[1]); o[6] = f2bf(v1[2]); o[7] = f2bf(v1[3]);
    *(bf16x8*)(xb + (size_t)i * 8) = o;
}

// Occupancy: LDS = 4*16*72*2 = 9216 B; __launch_bounds__(256,4) caps VGPR <=128
// -> 16 waves/CU (50%), up from 31% (ebuf made LDS the limiter at 43 KB/block).
template<bool XB>
__global__ __launch_bounds__(256, 4)
void edge_update(const float* __restrict__ x, const short* __restrict__ xb,
                 const int* __restrict__ ei, const float* __restrict__ e,
                 const float* __restrict__ b1, const float* __restrict__ b2,
                 const short* __restrict__ W1T, const short* __restrict__ W2T,
                 float* __restrict__ out) {
    __shared__ short hbuf[4][16 * 72];    // h re-layout (C-layout -> A/B-layout), per-wave

    const int tid  = threadIdx.x;
    const int wave = tid >> 6;
    const int lane = tid & 63;
    const int m    = lane & 15;      // fragment row / output-edge index
    const int q    = lane >> 4;      // quad
    const int kq   = q * 8;

    short* hb = &hbuf[wave][0];

    // ---- hoist edge-index loads for BOTH tiles (kills ei->gather chain on t=1) ----
    int srcs[2], dsts[2];
    #pragma unroll
    for (int t = 0; t < 2; ++t) {
        const int tile = blockIdx.x * 8 + wave * 2 + t;
        if (tile < NTILES) {
            const int edge = tile * 16 + m;
            srcs[t] = ei[edge];
            dsts[t] = ei[EN + edge];
        } else { srcs[t] = 0; dsts[t] = 0; }
    }

    #pragma unroll
    for (int t = 0; t < 2; ++t) {
        const int tile = blockIdx.x * 8 + wave * 2 + t;
        if (tile >= NTILES) continue;
        const int ebase = tile * 16;
        const int src = srcs[t];
        const int dst = dsts[t];

        // ---- issue all per-tile input loads up front ----
        bf16x8 as[4], ad[4], ae[4];
        if (XB) {
            const short* ps = xb + (size_t)src * DN;
            const short* pd = xb + (size_t)dst * DN;
            #pragma unroll
            for (int ks = 0; ks < 4; ++ks) {
                as[ks] = *(const bf16x8*)(ps + ks * 32 + kq);
                ad[ks] = *(const bf16x8*)(pd + ks * 32 + kq);
            }
        } else {
            const float* rs = x + (size_t)src * DN;
            const float* rd = x + (size_t)dst * DN;
            #pragma unroll
            for (int ks = 0; ks < 4; ++ks) {
                f32x4 s0 = *(const f32x4*)(rs + ks * 32 + kq);
                f32x4 s1 = *(const f32x4*)(rs + ks * 32 + kq + 4);
                f32x4 d0 = *(const f32x4*)(rd + ks * 32 + kq);
                f32x4 d1 = *(const f32x4*)(rd + ks * 32 + kq + 4);
                bf16x8 a, b;
                a[0]=f2bf(s0[0]); a[1]=f2bf(s0[1]); a[2]=f2bf(s0[2]); a[3]=f2bf(s0[3]);
                a[4]=f2bf(s1[0]); a[5]=f2bf(s1[1]); a[6]=f2bf(s1[2]); a[7]=f2bf(s1[3]);
                b[0]=f2bf(d0[0]); b[1]=f2bf(d0[1]); b[2]=f2bf(d0[2]); b[3]=f2bf(d0[3]);
                b[4]=f2bf(d1[0]); b[5]=f2bf(d1[1]); b[6]=f2bf(d1[2]); b[7]=f2bf(d1[3]);
                as[ks] = a; ad[ks] = b;
            }
        }

        // e in MFMA-A layout (feeds GEMM1 only; residual is re-read vectorized in epilogue)
        {
            const float* re = e + (size_t)(ebase + m) * DN;
            f32x4 ev[8];
            #pragma unroll
            for (int ks = 0; ks < 4; ++ks) {
                ev[2*ks]   = *(const f32x4*)(re + ks * 32 + kq);
                ev[2*ks+1] = *(const f32x4*)(re + ks * 32 + kq + 4);
            }
            #pragma unroll
            for (int ks = 0; ks < 4; ++ks) {
                bf16x8 a;
                a[0]=f2bf(ev[2*ks][0]); a[1]=f2bf(ev[2*ks][1]); a[2]=f2bf(ev[2*ks][2]); a[3]=f2bf(ev[2*ks][3]);
                a[4]=f2bf(ev[2*ks+1][0]); a[5]=f2bf(ev[2*ks+1][1]); a[6]=f2bf(ev[2*ks+1][2]); a[7]=f2bf(ev[2*ks+1][3]);
                ae[ks] = a;
            }
        }

        // ---------------- GEMM1: [16,384] @ [384,64] -> h[16,64] ----------------
        f32x4 acc1[4];
        #pragma unroll
        for (int nt = 0; nt < 4; ++nt) acc1[nt] = (f32x4){0.f, 0.f, 0.f, 0.f};

        #pragma unroll
        for (int ks = 0; ks < 12; ++ks) {
            bf16x8 a = (ks < 4) ? as[ks] : (ks < 8) ? ad[ks - 4] : ae[ks - 8];
            const int kglob = ks * 32 + kq;
            #pragma unroll
            for (int nt = 0; nt < 4; ++nt) {
                bf16x8 b = *(const bf16x8*)(W1T + (m + 16 * nt) * DIN + kglob);
                acc1[nt] = __builtin_amdgcn_mfma_f32_16x16x32_bf16(a, b, acc1[nt], 0, 0, 0);
            }
        }

        // bias + ReLU, h -> LDS row-major [row][hid]
        #pragma unroll
        for (int nt = 0; nt < 4; ++nt) {
            const int col = m + 16 * nt;
            const float bv = b1[col];
            #pragma unroll
            for (int r = 0; r < 4; ++r) {
                float h = acc1[nt][r] + bv;
                h = h > 0.f ? h : 0.f;
                hb[(q * 4 + r) * 72 + col] = f2bf(h);
            }
        }

        // ------- GEMM2 (operands SWAPPED -> transposed C layout): out^T = W2^T @ h^T -------
        // lane (m,q), reg r now holds out[edge ebase+m][d = 16*nt + 4*q + r]:
        // 4 consecutive feature dims per lane -> f32x4 epilogue loads/stores.
        bf16x8 ha0 = *(const bf16x8*)(hb + m * 72 + kq);
        bf16x8 ha1 = *(const bf16x8*)(hb + m * 72 + 32 + kq);

        f32x4 acc2[8];
        #pragma unroll
        for (int nt = 0; nt < 8; ++nt) acc2[nt] = (f32x4){0.f, 0.f, 0.f, 0.f};

        #pragma unroll
        for (int nt = 0; nt < 8; ++nt) {
            const short* wp = W2T + (m + 16 * nt) * HID + kq;
            bf16x8 b0  = *(const bf16x8*)wp;
            bf16x8 b1v = *(const bf16x8*)(wp + 32);
            acc2[nt] = __builtin_amdgcn_mfma_f32_16x16x32_bf16(b0,  ha0, acc2[nt], 0, 0, 0);
            acc2[nt] = __builtin_amdgcn_mfma_f32_16x16x32_bf16(b1v, ha1, acc2[nt], 0, 0, 0);
        }

        // ---------------- epilogue: out = e + (h@W2) + b2, fully vectorized ----------------
        // e re-read is L2-hot (fetched ~1-2k cycles ago by this CU's A-layout read).
        {
            const float* er   = e   + (size_t)(ebase + m) * DN + q * 4;
            float*       orow = out + (size_t)(ebase + m) * DN + q * 4;
            #pragma unroll
            for (int nt = 0; nt < 8; ++nt) {
                f32x4 evv = *(const f32x4*)(er + nt * 16);
                f32x4 bv  = *(const f32x4*)(b2 + nt * 16 + q * 4);
                f32x4 o = evv + acc2[nt] + bv;
                __builtin_nontemporal_store(o, (f32x4*)(orow + nt * 16));  // dead stores: don't thrash L1/L2
            }
        }
    }
}

extern "C" void kernel_launch(void* const* d_in, const int* in_sizes, int n_in,
                              void* d_out, int out_size, void* d_ws, size_t ws_size,
                              hipStream_t stream) {
    const float* x  = (const float*)d_in[0];
    const int*   ei = (const int*)d_in[1];
    const float* e  = (const float*)d_in[2];
    const float* W1 = (const float*)d_in[3];
    const float* b1 = (const float*)d_in[4];
    const float* W2 = (const float*)d_in[5];
    const float* b2 = (const float*)d_in[6];
    float* out = (float*)d_out;

    short* W1T = (short*)d_ws;                 // 64*384 bf16  = 49152 B
    short* W2T = W1T + HID * DIN;              // 128*64 bf16  = 16384 B
    short* xb  = W2T + HID * DN;               // 50000*128 bf16 = 12.8 MB
    const size_t need_xb = (size_t)(HID * DIN + HID * DN + NN * DN) * 2;

    prep_weights<<<96, 256, 0, stream>>>(W1, W2, W1T, W2T);

    const int nblocks = (NTILES + 7) / 8;      // 8 tiles (128 edges) per block
    if (ws_size >= need_xb) {
        prep_x<<<(NN * DN / 8 + 255) / 256, 256, 0, stream>>>(x, xb);
        edge_update<true><<<nblocks, 256, 0, stream>>>(x, xb, ei, e, b1, b2, W1T, W2T, out);
    } else {
        edge_update<false><<<nblocks, 256, 0, stream>>>(x, xb, ei, e, b1, b2, W1T, W2T, out);
    }
}

// Round 3
// 662.803 us; speedup vs baseline: 1.0820x; 1.0820x over previous
//
#include <hip/hip_runtime.h>

#define NN   50000        // nodes
#define EN   500000       // edges
#define DN   128          // node feature dim == edge feature dim
#define DIN  384          // 2*DN + DE
#define HID  64
#define NTILES 31250      // EN / 16 (exact)
#define EST  132          // ebuf row stride in floats (4*132 % 128B: breaks bank aliasing both layouts)

typedef __attribute__((ext_vector_type(8))) short bf16x8;
typedef __attribute__((ext_vector_type(4))) float f32x4;

__device__ __forceinline__ short f2bf(float f) {
    union { float f; unsigned u; } v; v.f = f;
    return (short)((v.u + 0x7FFFu + ((v.u >> 16) & 1u)) >> 16);  // RNE
}

// W1 [384,64] f32 -> W1T [64][384] bf16 ; W2 [64,128] f32 -> W2T [128][64] bf16
__global__ void prep_weights(const float* __restrict__ W1, const float* __restrict__ W2,
                             short* __restrict__ W1T, short* __restrict__ W2T) {
    int i = blockIdx.x * 256 + threadIdx.x;
    if (i < DIN * HID) {
        int k = i / HID, n = i % HID;
        W1T[n * DIN + k] = f2bf(W1[i]);
    }
    if (i < HID * DN) {
        int k = i / DN, d = i % DN;
        W2T[d * HID + k] = f2bf(W2[i]);
    }
}

// x [NN,128] f32 -> xb [NN,128] bf16 (halves gather bytes, removes inner-loop converts)
__global__ void prep_x(const float* __restrict__ x, short* __restrict__ xb) {
    int i = blockIdx.x * 256 + threadIdx.x;   // one thread per 8 elements
    if (i >= NN * DN / 8) return;
    const float* p = x + (size_t)i * 8;
    f32x4 v0 = *(const f32x4*)p;
    f32x4 v1 = *(const f32x4*)(p + 4);
    bf16x8 o;
    o[0] = f2bf(v0[0]); o[1] = f2bf(v0[1]); o[2] = f2bf(v0[2]); o[3] = f2bf(v0[3]);
    o[4] = f2bf(v1[0]); o[5] = f2bf(v1[1]); o[6] = f2bf(v1[2]); o[7] = f2bf(v1[3]);
    *(bf16x8*)(xb + (size_t)i * 8) = o;
}

// GEMMs + epilogue for one 16-edge tile. Inputs (gathers, e) already in registers.
__device__ __forceinline__ void tile_main(
    int tile, bool valid, int m, int q, int kq,
    const bf16x8* as, const bf16x8* ad, const bf16x8* ae,
    const float* bb1, float* eb, short* hb,
    const short* __restrict__ W1T, const short* __restrict__ W2T,
    const float* __restrict__ b2, float* __restrict__ out)
{
    if (!valid) return;
    const int ebase = tile * 16;

    // ---------------- GEMM1: [16,384] @ [384,64] -> h[16,64] ----------------
    f32x4 acc1[4];
    #pragma unroll
    for (int nt = 0; nt < 4; ++nt) acc1[nt] = (f32x4){0.f, 0.f, 0.f, 0.f};

    #pragma unroll
    for (int ks = 0; ks < 12; ++ks) {
        bf16x8 a = (ks < 4) ? as[ks] : (ks < 8) ? ad[ks - 4] : ae[ks - 8];
        const int kglob = ks * 32 + kq;
        #pragma unroll
        for (int nt = 0; nt < 4; ++nt) {
            bf16x8 b = *(const bf16x8*)(W1T + (m + 16 * nt) * DIN + kglob);
            acc1[nt] = __builtin_amdgcn_mfma_f32_16x16x32_bf16(a, b, acc1[nt], 0, 0, 0);
        }
    }

    // bias + ReLU, h -> LDS row-major [edge-row][hid] (C-layout -> A-layout fixup)
    #pragma unroll
    for (int nt = 0; nt < 4; ++nt) {
        const int col = m + 16 * nt;
        const float bv = bb1[nt];
        #pragma unroll
        for (int r = 0; r < 4; ++r) {
            float h = acc1[nt][r] + bv;
            h = h > 0.f ? h : 0.f;
            hb[(q * 4 + r) * 72 + col] = f2bf(h);
        }
    }

    // ------- GEMM2 (operands swapped -> transposed C): lane holds 4 consecutive d -------
    bf16x8 ha0 = *(const bf16x8*)(hb + m * 72 + kq);
    bf16x8 ha1 = *(const bf16x8*)(hb + m * 72 + 32 + kq);

    f32x4 acc2[8];
    #pragma unroll
    for (int nt = 0; nt < 8; ++nt) acc2[nt] = (f32x4){0.f, 0.f, 0.f, 0.f};

    #pragma unroll
    for (int nt = 0; nt < 8; ++nt) {
        const short* wp = W2T + (m + 16 * nt) * HID + kq;
        bf16x8 b0  = *(const bf16x8*)wp;
        bf16x8 b1v = *(const bf16x8*)(wp + 32);
        acc2[nt] = __builtin_amdgcn_mfma_f32_16x16x32_bf16(b0,  ha0, acc2[nt], 0, 0, 0);
        acc2[nt] = __builtin_amdgcn_mfma_f32_16x16x32_bf16(b1v, ha1, acc2[nt], 0, 0, 0);
    }

    // ---------------- epilogue: out = e(LDS) + (h@W2) + b2, vectorized ----------------
    const float* ebr  = eb  + m * EST + q * 4;
    float*       orow = out + (size_t)(ebase + m) * DN + q * 4;
    #pragma unroll
    for (int nt = 0; nt < 8; ++nt) {
        f32x4 evv = *(const f32x4*)(ebr + nt * 16);
        f32x4 bv  = *(const f32x4*)(b2 + nt * 16 + q * 4);
        *(f32x4*)(orow + nt * 16) = evv + acc2[nt] + bv;   // plain store: full-line WC in L2
    }
}

// LDS 43008 B/block -> 3 blocks/CU (12 waves); bound VGPR at ~170 so both tiles'
// inputs can be in flight simultaneously (latency-bound kernel: MLP is the lever).
template<bool XB>
__global__ __launch_bounds__(256, 3)
void edge_update(const float* __restrict__ x, const short* __restrict__ xb,
                 const int* __restrict__ ei, const float* __restrict__ e,
                 const float* __restrict__ b1, const float* __restrict__ b2,
                 const short* __restrict__ W1T, const short* __restrict__ W2T,
                 float* __restrict__ out) {
    __shared__ float ebuf[4][16 * EST];   // e-tile stash: epilogue residual from LDS
    __shared__ short hbuf[4][16 * 72];    // h re-layout (C-layout -> A-layout)

    const int tid  = threadIdx.x;
    const int wave = tid >> 6;
    const int lane = tid & 63;
    const int m    = lane & 15;
    const int q    = lane >> 4;
    const int kq   = q * 8;

    float* eb = &ebuf[wave][0];
    short* hb = &hbuf[wave][0];

    const int tile0 = blockIdx.x * 8 + wave * 2;
    const int tile1 = tile0 + 1;
    const bool v0 = (tile0 < NTILES);
    const bool v1 = (tile1 < NTILES);

    // ---- edge indices for BOTH tiles first (head of every gather dep-chain) ----
    int src0 = 0, dst0 = 0, src1 = 0, dst1 = 0;
    if (v0) { src0 = ei[tile0 * 16 + m]; dst0 = ei[EN + tile0 * 16 + m]; }
    if (v1) { src1 = ei[tile1 * 16 + m]; dst1 = ei[EN + tile1 * 16 + m]; }

    float bb1[4];
    #pragma unroll
    for (int nt = 0; nt < 4; ++nt) bb1[nt] = b1[m + 16 * nt];

    // ---- issue BOTH tiles' gathers up front: ~16 independent 16B loads/lane ----
    bf16x8 as0[4], ad0[4], as1[4], ad1[4];
    if (XB) {
        const short* ps0 = xb + (size_t)src0 * DN;
        const short* pd0 = xb + (size_t)dst0 * DN;
        const short* ps1 = xb + (size_t)src1 * DN;
        const short* pd1 = xb + (size_t)dst1 * DN;
        #pragma unroll
        for (int ks = 0; ks < 4; ++ks) {
            as0[ks] = *(const bf16x8*)(ps0 + ks * 32 + kq);
            ad0[ks] = *(const bf16x8*)(pd0 + ks * 32 + kq);
        }
        #pragma unroll
        for (int ks = 0; ks < 4; ++ks) {
            as1[ks] = *(const bf16x8*)(ps1 + ks * 32 + kq);
            ad1[ks] = *(const bf16x8*)(pd1 + ks * 32 + kq);
        }
    } else {
        const float* rs0 = x + (size_t)src0 * DN;
        const float* rd0 = x + (size_t)dst0 * DN;
        const float* rs1 = x + (size_t)src1 * DN;
        const float* rd1 = x + (size_t)dst1 * DN;
        #pragma unroll
        for (int ks = 0; ks < 4; ++ks) {
            f32x4 s0 = *(const f32x4*)(rs0 + ks * 32 + kq);
            f32x4 s1 = *(const f32x4*)(rs0 + ks * 32 + kq + 4);
            f32x4 d0 = *(const f32x4*)(rd0 + ks * 32 + kq);
            f32x4 d1 = *(const f32x4*)(rd0 + ks * 32 + kq + 4);
            bf16x8 a, b;
            a[0]=f2bf(s0[0]); a[1]=f2bf(s0[1]); a[2]=f2bf(s0[2]); a[3]=f2bf(s0[3]);
            a[4]=f2bf(s1[0]); a[5]=f2bf(s1[1]); a[6]=f2bf(s1[2]); a[7]=f2bf(s1[3]);
            b[0]=f2bf(d0[0]); b[1]=f2bf(d0[1]); b[2]=f2bf(d0[2]); b[3]=f2bf(d0[3]);
            b[4]=f2bf(d1[0]); b[5]=f2bf(d1[1]); b[6]=f2bf(d1[2]); b[7]=f2bf(d1[3]);
            as0[ks] = a; ad0[ks] = b;
        }
        #pragma unroll
        for (int ks = 0; ks < 4; ++ks) {
            f32x4 s0 = *(const f32x4*)(rs1 + ks * 32 + kq);
            f32x4 s1 = *(const f32x4*)(rs1 + ks * 32 + kq + 4);
            f32x4 d0 = *(const f32x4*)(rd1 + ks * 32 + kq);
            f32x4 d1 = *(const f32x4*)(rd1 + ks * 32 + kq + 4);
            bf16x8 a, b;
            a[0]=f2bf(s0[0]); a[1]=f2bf(s0[1]); a[2]=f2bf(s0[2]); a[3]=f2bf(s0[3]);
            a[4]=f2bf(s1[0]); a[5]=f2bf(s1[1]); a[6]=f2bf(s1[2]); a[7]=f2bf(s1[3]);
            b[0]=f2bf(d0[0]); b[1]=f2bf(d0[1]); b[2]=f2bf(d0[2]); b[3]=f2bf(d0[3]);
            b[4]=f2bf(d1[0]); b[5]=f2bf(d1[1]); b[6]=f2bf(d1[2]); b[7]=f2bf(d1[3]);
            as1[ks] = a; ad1[ks] = b;
        }
    }

    // ---- e tile0: load (A-layout stream), stash to LDS, convert to bf16 frags ----
    bf16x8 ae0[4];
    if (v0) {
        const float* re = e + (size_t)(tile0 * 16 + m) * DN;
        f32x4 ev[8];
        #pragma unroll
        for (int ks = 0; ks < 4; ++ks) {
            ev[2*ks]   = *(const f32x4*)(re + ks * 32 + kq);
            ev[2*ks+1] = *(const f32x4*)(re + ks * 32 + kq + 4);
        }
        #pragma unroll
        for (int ks = 0; ks < 4; ++ks) {
            *(f32x4*)(eb + m * EST + ks * 32 + kq)     = ev[2*ks];
            *(f32x4*)(eb + m * EST + ks * 32 + kq + 4) = ev[2*ks+1];
            bf16x8 a;
            a[0]=f2bf(ev[2*ks][0]);   a[1]=f2bf(ev[2*ks][1]);   a[2]=f2bf(ev[2*ks][2]);   a[3]=f2bf(ev[2*ks][3]);
            a[4]=f2bf(ev[2*ks+1][0]); a[5]=f2bf(ev[2*ks+1][1]); a[6]=f2bf(ev[2*ks+1][2]); a[7]=f2bf(ev[2*ks+1][3]);
            ae0[ks] = a;
        }
    }

    // ---- e tile1: issue loads NOW so they fly during tile0's GEMMs ----
    f32x4 ev1[8];
    if (v1) {
        const float* re = e + (size_t)(tile1 * 16 + m) * DN;
        #pragma unroll
        for (int ks = 0; ks < 4; ++ks) {
            ev1[2*ks]   = *(const f32x4*)(re + ks * 32 + kq);
            ev1[2*ks+1] = *(const f32x4*)(re + ks * 32 + kq + 4);
        }
    }

    tile_main(tile0, v0, m, q, kq, as0, ad0, ae0, bb1, eb, hb, W1T, W2T, b2, out);

    // tile1: stash e (AFTER tile0 epilogue consumed eb) + convert, then compute
    bf16x8 ae1[4];
    if (v1) {
        #pragma unroll
        for (int ks = 0; ks < 4; ++ks) {
            *(f32x4*)(eb + m * EST + ks * 32 + kq)     = ev1[2*ks];
            *(f32x4*)(eb + m * EST + ks * 32 + kq + 4) = ev1[2*ks+1];
            bf16x8 a;
            a[0]=f2bf(ev1[2*ks][0]);   a[1]=f2bf(ev1[2*ks][1]);   a[2]=f2bf(ev1[2*ks][2]);   a[3]=f2bf(ev1[2*ks][3]);
            a[4]=f2bf(ev1[2*ks+1][0]); a[5]=f2bf(ev1[2*ks+1][1]); a[6]=f2bf(ev1[2*ks+1][2]); a[7]=f2bf(ev1[2*ks+1][3]);
            ae1[ks] = a;
        }
    }
    tile_main(tile1, v1, m, q, kq, as1, ad1, ae1, bb1, eb, hb, W1T, W2T, b2, out);
}

extern "C" void kernel_launch(void* const* d_in, const int* in_sizes, int n_in,
                              void* d_out, int out_size, void* d_ws, size_t ws_size,
                              hipStream_t stream) {
    const float* x  = (const float*)d_in[0];
    const int*   ei = (const int*)d_in[1];
    const float* e  = (const float*)d_in[2];
    const float* W1 = (const float*)d_in[3];
    const float* b1 = (const float*)d_in[4];
    const float* W2 = (const float*)d_in[5];
    const float* b2 = (const float*)d_in[6];
    float* out = (float*)d_out;

    short* W1T = (short*)d_ws;                 // 64*384 bf16  = 49152 B
    short* W2T = W1T + HID * DIN;              // 128*64 bf16  = 16384 B
    short* xb  = W2T + HID * DN;               // 50000*128 bf16 = 12.8 MB
    const size_t need_xb = (size_t)(HID * DIN + HID * DN + NN * DN) * 2;

    prep_weights<<<96, 256, 0, stream>>>(W1, W2, W1T, W2T);

    const int nblocks = (NTILES + 7) / 8;      // 8 tiles (128 edges) per block
    if (ws_size >= need_xb) {
        prep_x<<<(NN * DN / 8 + 255) / 256, 256, 0, stream>>>(x, xb);
        edge_update<true><<<nblocks, 256, 0, stream>>>(x, xb, ei, e, b1, b2, W1T, W2T, out);
    } else {
        edge_update<false><<<nblocks, 256, 0, stream>>>(x, xb, ei, e, b1, b2, W1T, W2T, out);
    }
}